// Round 5
// baseline (249.332 us; speedup 1.0000x reference)
//
#include <hip/hip_runtime.h>
#include <math.h>

#define CCH 128
#define RR  32
#define S_SP 131072   // 32*64*64
#define BATCH 4
#define EPSV 1e-5f

// ws layout (floats):
// [0,1024)       partial sums  s  (1024 half-row blocks)
// [1024,2048)    partial sums  q
// [2048,18432)   w1t[b][c][r] = W1[r][c]*a[b][c]   (r contiguous)
// [18432,18560)  bias[b][r]   = sum_c W1[r][c]*(beta-mean*a)[c]
// [18560,22656)  w2s[c][r]    = W2[c][r]*channel_scale[c]
#define PART_S 0
#define PART_Q 1024
#define W1T_OFF 2048
#define BIAS_OFF 18432
#define W2S_OFF 18560

__global__ __launch_bounds__(256) void stats1_kernel(const float* __restrict__ x,
                                                     float* __restrict__ ws) {
  const int pb = blockIdx.x;               // bc = pb>>1, half = pb&1
  const float* xp = x + (size_t)pb * (S_SP / 2);
  float s = 0.f, q = 0.f;
  for (int i = threadIdx.x * 4; i < S_SP / 2; i += 256 * 4) {
    float4 v = *reinterpret_cast<const float4*>(xp + i);
    s += v.x + v.y + v.z + v.w;
    q += v.x * v.x + v.y * v.y + v.z * v.z + v.w * v.w;
  }
  for (int off = 32; off > 0; off >>= 1) {
    s += __shfl_down(s, off, 64);
    q += __shfl_down(q, off, 64);
  }
  __shared__ float ss[4], qq[4];
  const int wave = threadIdx.x >> 6, lane = threadIdx.x & 63;
  if (lane == 0) { ss[wave] = s; qq[wave] = q; }
  __syncthreads();
  if (threadIdx.x == 0) {
    ws[PART_S + pb] = ss[0] + ss[1] + ss[2] + ss[3];
    ws[PART_Q + pb] = qq[0] + qq[1] + qq[2] + qq[3];
  }
}

__global__ __launch_bounds__(256) void prep_kernel(const float* __restrict__ W1,
                                                   const float* __restrict__ W2,
                                                   const float* __restrict__ scale,
                                                   const float* __restrict__ gamma,
                                                   const float* __restrict__ beta,
                                                   float* __restrict__ ws) {
  const int b = blockIdx.x;
  __shared__ float aS[CCH], bbS[CCH];
  if (threadIdx.x < CCH) {
    const int c = threadIdx.x;
    const int bc = b * CCH + c;
    const float S = ws[PART_S + 2 * bc] + ws[PART_S + 2 * bc + 1];
    const float Q = ws[PART_Q + 2 * bc] + ws[PART_Q + 2 * bc + 1];
    const float mean = S / (float)S_SP;
    const float var  = Q / (float)S_SP - mean * mean;    // biased, matches ref
    const float rstd = rsqrtf(var + EPSV);
    const float a = rstd * gamma[c];
    aS[c]  = a;
    bbS[c] = beta[c] - mean * a;
  }
  __syncthreads();
  float* w1t = ws + W1T_OFF + b * CCH * RR;
  for (int idx = threadIdx.x; idx < CCH * RR; idx += 256) {
    const int c = idx >> 5, r = idx & 31;
    w1t[idx] = W1[r * CCH + c] * aS[c];
  }
  if (threadIdx.x < RR) {
    const int r = threadIdx.x;
    float sum = 0.f;
    for (int c = 0; c < CCH; ++c) sum += W1[r * CCH + c] * bbS[c];
    ws[BIAS_OFF + b * RR + r] = sum;
  }
  if (b == 0) {
    for (int idx = threadIdx.x; idx < CCH * RR; idx += 256) {
      const int c = idx >> 5;
      ws[W2S_OFF + idx] = W2[idx] * scale[c];   // W2 is (C,R) row-major
    }
  }
}

// 1 position per thread (dword loads, still fully coalesced: 256B/wave-inst).
// 32 accumulators -> target VGPR<=64 -> 8 waves/SIMD.
// Single 16KB LDS weight buffer, reused: stage W1 -> pass1 -> stage W2 -> pass2.
// 8 blocks/CU x 16.4KB = 131KB LDS < 160KB.
__global__ __launch_bounds__(256, 8) void mlp_kernel(const float* __restrict__ x,
                                                     const float* __restrict__ ws,
                                                     float* __restrict__ out) {
  const int b = blockIdx.y;
  const int s = blockIdx.x * 256 + threadIdx.x;
  const float* xc = x + (size_t)b * CCH * S_SP + s;
  float*       oc = out + (size_t)b * CCH * S_SP + s;

  __shared__ float wls[CCH * RR];
  __shared__ float biass[RR];
  {
    const float* w1g = ws + W1T_OFF + b * CCH * RR;
    for (int i = threadIdx.x; i < CCH * RR; i += 256) wls[i] = w1g[i];
    if (threadIdx.x < RR) biass[threadIdx.x] = ws[BIAS_OFF + b * RR + threadIdx.x];
  }
  __syncthreads();

  float p[RR];
  #pragma unroll
  for (int r = 0; r < RR; ++r) p[r] = biass[r];

#define LDX(c) (xc[(size_t)(c) * S_SP])

#define FMA1(c, v)                                                        \
  {                                                                       \
    const float4* w4_ = reinterpret_cast<const float4*>(wls + (c) * RR);  \
    _Pragma("unroll")                                                     \
    for (int rq = 0; rq < RR / 4; ++rq) {                                 \
      const float4 w = w4_[rq];                                           \
      p[4*rq+0] = fmaf((v), w.x, p[4*rq+0]);                              \
      p[4*rq+1] = fmaf((v), w.y, p[4*rq+1]);                              \
      p[4*rq+2] = fmaf((v), w.z, p[4*rq+2]);                              \
      p[4*rq+3] = fmaf((v), w.w, p[4*rq+3]);                              \
    }                                                                     \
  }

  // ---- pass 1: proj = w1t @ x + bias, depth-4 pipelined dword loads ----
  {
    float v0 = LDX(0), v1 = LDX(1), v2 = LDX(2), v3 = LDX(3);
    for (int c4 = 0; c4 < 31; ++c4) {
      const int c = c4 * 4;
      FMA1(c + 0, v0); v0 = LDX(c + 4);
      FMA1(c + 1, v1); v1 = LDX(c + 5);
      FMA1(c + 2, v2); v2 = LDX(c + 6);
      FMA1(c + 3, v3); v3 = LDX(c + 7);
    }
    FMA1(124, v0); FMA1(125, v1); FMA1(126, v2); FMA1(127, v3);
  }

  #pragma unroll
  for (int r = 0; r < RR; ++r) p[r] = fminf(fmaxf(p[r], 0.f), 6.f);

  __syncthreads();   // everyone done reading w1
  {
    const float* w2g = ws + W2S_OFF;
    for (int i = threadIdx.x; i < CCH * RR; i += 256) wls[i] = w2g[i];
  }
  __syncthreads();

#define FMA2(c, v)                                                        \
  {                                                                       \
    const float4* w4_ = reinterpret_cast<const float4*>(wls + (c) * RR);  \
    float r0 = 0.f;                                                       \
    _Pragma("unroll")                                                     \
    for (int rq = 0; rq < RR / 4; ++rq) {                                 \
      const float4 w = w4_[rq];                                           \
      r0 = fmaf(p[4*rq+0], w.x, r0);                                      \
      r0 = fmaf(p[4*rq+1], w.y, r0);                                      \
      r0 = fmaf(p[4*rq+2], w.z, r0);                                      \
      r0 = fmaf(p[4*rq+3], w.w, r0);                                      \
    }                                                                     \
    __builtin_nontemporal_store(r0 + (v), oc + (size_t)(c) * S_SP);       \
  }

  // ---- pass 2: out = w2s @ act + x, depth-4 pipelined dword loads ----
  {
    float v0 = LDX(0), v1 = LDX(1), v2 = LDX(2), v3 = LDX(3);
    for (int c4 = 0; c4 < 31; ++c4) {
      const int c = c4 * 4;
      FMA2(c + 0, v0); v0 = LDX(c + 4);
      FMA2(c + 1, v1); v1 = LDX(c + 5);
      FMA2(c + 2, v2); v2 = LDX(c + 6);
      FMA2(c + 3, v3); v3 = LDX(c + 7);
    }
    FMA2(124, v0); FMA2(125, v1); FMA2(126, v2); FMA2(127, v3);
  }
}

extern "C" void kernel_launch(void* const* d_in, const int* in_sizes, int n_in,
                              void* d_out, int out_size, void* d_ws, size_t ws_size,
                              hipStream_t stream) {
  const float* x     = (const float*)d_in[0];
  const float* scale = (const float*)d_in[1];
  const float* W1    = (const float*)d_in[2];
  const float* W2    = (const float*)d_in[3];
  const float* gamma = (const float*)d_in[4];
  const float* beta  = (const float*)d_in[5];
  float* out = (float*)d_out;
  float* ws  = (float*)d_ws;

  stats1_kernel<<<BATCH * CCH * 2, 256, 0, stream>>>(x, ws);
  prep_kernel<<<BATCH, 256, 0, stream>>>(W1, W2, scale, gamma, beta, ws);
  dim3 grid(S_SP / 256, BATCH);
  mlp_kernel<<<grid, 256, 0, stream>>>(x, ws, out);
}

// Round 6
// 180.932 us; speedup vs baseline: 1.3780x; 1.3780x over previous
//
#include <hip/hip_runtime.h>
#include <math.h>

#define CCH 128
#define RR  32
#define S_SP 131072   // 32*64*64
#define BATCH 4
#define EPSV 1e-5f

typedef float f32x2 __attribute__((ext_vector_type(2)));

// ws layout (floats):
// [0,1024)       partial sums  s  (1024 half-row blocks)
// [1024,2048)    partial sums  q
// [2048,18432)   w1t[b][c][r] = W1[r][c]*a[b][c]   (r contiguous)
// [18432,18560)  bias[b][r]   = sum_c W1[r][c]*(beta-mean*a)[c]
// [18560,22656)  w2s[c][r]    = W2[c][r]*channel_scale[c]
#define PART_S 0
#define PART_Q 1024
#define W1T_OFF 2048
#define BIAS_OFF 18432
#define W2S_OFF 18560

__global__ __launch_bounds__(256) void stats1_kernel(const float* __restrict__ x,
                                                     float* __restrict__ ws) {
  const int pb = blockIdx.x;               // bc = pb>>1, half = pb&1
  const float* xp = x + (size_t)pb * (S_SP / 2);
  float s = 0.f, q = 0.f;
  for (int i = threadIdx.x * 4; i < S_SP / 2; i += 256 * 4) {
    float4 v = *reinterpret_cast<const float4*>(xp + i);
    s += v.x + v.y + v.z + v.w;
    q += v.x * v.x + v.y * v.y + v.z * v.z + v.w * v.w;
  }
  for (int off = 32; off > 0; off >>= 1) {
    s += __shfl_down(s, off, 64);
    q += __shfl_down(q, off, 64);
  }
  __shared__ float ss[4], qq[4];
  const int wave = threadIdx.x >> 6, lane = threadIdx.x & 63;
  if (lane == 0) { ss[wave] = s; qq[wave] = q; }
  __syncthreads();
  if (threadIdx.x == 0) {
    ws[PART_S + pb] = ss[0] + ss[1] + ss[2] + ss[3];
    ws[PART_Q + pb] = qq[0] + qq[1] + qq[2] + qq[3];
  }
}

__global__ __launch_bounds__(256) void prep_kernel(const float* __restrict__ W1,
                                                   const float* __restrict__ W2,
                                                   const float* __restrict__ scale,
                                                   const float* __restrict__ gamma,
                                                   const float* __restrict__ beta,
                                                   float* __restrict__ ws) {
  const int b = blockIdx.x;
  __shared__ float aS[CCH], bbS[CCH];
  if (threadIdx.x < CCH) {
    const int c = threadIdx.x;
    const int bc = b * CCH + c;
    const float S = ws[PART_S + 2 * bc] + ws[PART_S + 2 * bc + 1];
    const float Q = ws[PART_Q + 2 * bc] + ws[PART_Q + 2 * bc + 1];
    const float mean = S / (float)S_SP;
    const float var  = Q / (float)S_SP - mean * mean;    // biased, matches ref
    const float rstd = rsqrtf(var + EPSV);
    const float a = rstd * gamma[c];
    aS[c]  = a;
    bbS[c] = beta[c] - mean * a;
  }
  __syncthreads();
  float* w1t = ws + W1T_OFF + b * CCH * RR;
  for (int idx = threadIdx.x; idx < CCH * RR; idx += 256) {
    const int c = idx >> 5, r = idx & 31;
    w1t[idx] = W1[r * CCH + c] * aS[c];
  }
  if (threadIdx.x < RR) {
    const int r = threadIdx.x;
    float sum = 0.f;
    for (int c = 0; c < CCH; ++c) sum += W1[r * CCH + c] * bbS[c];
    ws[BIAS_OFF + b * RR + r] = sum;
  }
  if (b == 0) {
    for (int idx = threadIdx.x; idx < CCH * RR; idx += 256) {
      const int c = idx >> 5;
      ws[W2S_OFF + idx] = W2[idx] * scale[c];   // W2 is (C,R) row-major
    }
  }
}

// 2 consecutive positions per thread (float2), 64 fp32 accumulators.
// Weights read DIRECTLY from global with wave-uniform addresses -> compiler
// scalarizes to s_load + SGPR operand in v_fma. No LDS, no barriers, no
// ds_read issue cost in the inner loop. Depth-4 x-load pipeline with named
// registers.
__global__ __launch_bounds__(256) void mlp_kernel(const float* __restrict__ x,
                                                  const float* __restrict__ ws,
                                                  float* __restrict__ out) {
  const int b = blockIdx.y;
  const int s = (blockIdx.x * 256 + threadIdx.x) * 2;
  const float* xc = x + (size_t)b * CCH * S_SP + s;
  float*       oc = out + (size_t)b * CCH * S_SP + s;

  const float4* w1g4 = reinterpret_cast<const float4*>(ws + W1T_OFF + (size_t)b * CCH * RR);
  const float4* w2g4 = reinterpret_cast<const float4*>(ws + W2S_OFF);
  const float*  bias = ws + BIAS_OFF + b * RR;

  float p0[RR], p1[RR];
  #pragma unroll
  for (int r = 0; r < RR; ++r) { const float bv = bias[r]; p0[r] = bv; p1[r] = bv; }

#define LDX(c) (*reinterpret_cast<const float2*>(xc + (size_t)(c) * S_SP))

#define FMA1(c, v)                                                        \
  {                                                                       \
    _Pragma("unroll")                                                     \
    for (int rq = 0; rq < RR / 4; ++rq) {                                 \
      const float4 w = w1g4[(c) * (RR / 4) + rq];                         \
      p0[4*rq+0] = fmaf((v).x, w.x, p0[4*rq+0]);                          \
      p0[4*rq+1] = fmaf((v).x, w.y, p0[4*rq+1]);                          \
      p0[4*rq+2] = fmaf((v).x, w.z, p0[4*rq+2]);                          \
      p0[4*rq+3] = fmaf((v).x, w.w, p0[4*rq+3]);                          \
      p1[4*rq+0] = fmaf((v).y, w.x, p1[4*rq+0]);                          \
      p1[4*rq+1] = fmaf((v).y, w.y, p1[4*rq+1]);                          \
      p1[4*rq+2] = fmaf((v).y, w.z, p1[4*rq+2]);                          \
      p1[4*rq+3] = fmaf((v).y, w.w, p1[4*rq+3]);                          \
    }                                                                     \
  }

  // ---- pass 1: proj = w1t @ x + bias ----
  {
    float2 v0 = LDX(0), v1 = LDX(1), v2 = LDX(2), v3 = LDX(3);
    for (int c4 = 0; c4 < 31; ++c4) {
      const int c = c4 * 4;
      FMA1(c + 0, v0); v0 = LDX(c + 4);
      FMA1(c + 1, v1); v1 = LDX(c + 5);
      FMA1(c + 2, v2); v2 = LDX(c + 6);
      FMA1(c + 3, v3); v3 = LDX(c + 7);
    }
    FMA1(124, v0); FMA1(125, v1); FMA1(126, v2); FMA1(127, v3);
  }

  #pragma unroll
  for (int r = 0; r < RR; ++r) {
    p0[r] = fminf(fmaxf(p0[r], 0.f), 6.f);
    p1[r] = fminf(fmaxf(p1[r], 0.f), 6.f);
  }

#define FMA2(c, v)                                                        \
  {                                                                       \
    float r0 = 0.f, r1 = 0.f;                                             \
    _Pragma("unroll")                                                     \
    for (int rq = 0; rq < RR / 4; ++rq) {                                 \
      const float4 w = w2g4[(c) * (RR / 4) + rq];                         \
      r0 = fmaf(p0[4*rq+0], w.x, r0);                                     \
      r0 = fmaf(p0[4*rq+1], w.y, r0);                                     \
      r0 = fmaf(p0[4*rq+2], w.z, r0);                                     \
      r0 = fmaf(p0[4*rq+3], w.w, r0);                                     \
      r1 = fmaf(p1[4*rq+0], w.x, r1);                                     \
      r1 = fmaf(p1[4*rq+1], w.y, r1);                                     \
      r1 = fmaf(p1[4*rq+2], w.z, r1);                                     \
      r1 = fmaf(p1[4*rq+3], w.w, r1);                                     \
    }                                                                     \
    f32x2 o_; o_.x = r0 + (v).x; o_.y = r1 + (v).y;                       \
    __builtin_nontemporal_store(o_,                                       \
        reinterpret_cast<f32x2*>(oc + (size_t)(c) * S_SP));               \
  }

  // ---- pass 2: out = w2s @ act + x ----
  {
    float2 v0 = LDX(0), v1 = LDX(1), v2 = LDX(2), v3 = LDX(3);
    for (int c4 = 0; c4 < 31; ++c4) {
      const int c = c4 * 4;
      FMA2(c + 0, v0); v0 = LDX(c + 4);
      FMA2(c + 1, v1); v1 = LDX(c + 5);
      FMA2(c + 2, v2); v2 = LDX(c + 6);
      FMA2(c + 3, v3); v3 = LDX(c + 7);
    }
    FMA2(124, v0); FMA2(125, v1); FMA2(126, v2); FMA2(127, v3);
  }
}

extern "C" void kernel_launch(void* const* d_in, const int* in_sizes, int n_in,
                              void* d_out, int out_size, void* d_ws, size_t ws_size,
                              hipStream_t stream) {
  const float* x     = (const float*)d_in[0];
  const float* scale = (const float*)d_in[1];
  const float* W1    = (const float*)d_in[2];
  const float* W2    = (const float*)d_in[3];
  const float* gamma = (const float*)d_in[4];
  const float* beta  = (const float*)d_in[5];
  float* out = (float*)d_out;
  float* ws  = (float*)d_ws;

  stats1_kernel<<<BATCH * CCH * 2, 256, 0, stream>>>(x, ws);
  prep_kernel<<<BATCH, 256, 0, stream>>>(W1, W2, scale, gamma, beta, ws);
  dim3 grid(S_SP / (256 * 2), BATCH);
  mlp_kernel<<<grid, 256, 0, stream>>>(x, ws, out);
}